// Round 1
// baseline (322.244 us; speedup 1.0000x reference)
//
#include <hip/hip_runtime.h>

// Problem constants (from reference)
#define DIM_IN   2048
#define FEAT     128
#define KP1      16385      // NCE_N + 1
#define NDATA    100000
#define BATCH    64
#define NCHUNK   16         // k-chunks per (side,b) in nce kernel

constexpr float NCE_T_INV = 1.0f / 0.07f;
constexpr float M_CONST   = 16384.0f / 100000.0f;   // NCE_N / N_DATA
constexpr float EPS_C     = 1e-7f;

// ---------------------------------------------------------------------------
// Kernel 1: h = l2norm(feat @ w.T + b) for both sides.
// One block per (side, b). 256 threads: d = t&127, half = t>>7 splits the
// 2048-dim dot in two. feat row staged in LDS; w rows read lane-per-row
// (each lane consumes a contiguous 4KB half-row via float4 -> full line use,
// 64 blocks/side re-read the 1MB w -> L2-resident).
// ---------------------------------------------------------------------------
__global__ void __launch_bounds__(256) embed_kernel(
    const float* __restrict__ feat_s, const float* __restrict__ feat_t,
    const float* __restrict__ w_s, const float* __restrict__ b_s,
    const float* __restrict__ w_t, const float* __restrict__ b_t,
    float* __restrict__ v_out)
{
    const int blk  = blockIdx.x;      // side*64 + b
    const int side = blk >> 6;
    const int b    = blk & 63;
    const float* feat = (side == 0 ? feat_s : feat_t) + (size_t)b * DIM_IN;
    const float* w    = (side == 0 ? w_s : w_t);
    const float* bias = (side == 0 ? b_s : b_t);

    __shared__ float sfeat[DIM_IN];
    __shared__ float part[2][FEAT];
    __shared__ float wsum[2];

    const int t = threadIdx.x;
    // coalesced float4 stage of the feat row (8 KB)
    {
        const float4* f4 = (const float4*)feat;
        float4* s4 = (float4*)sfeat;
        for (int j = t; j < DIM_IN / 4; j += 256) s4[j] = f4[j];
    }
    __syncthreads();

    const int d = t & 127, half = t >> 7;
    const float4* w4 = (const float4*)(w + (size_t)d * DIM_IN + half * (DIM_IN / 2));
    const float*  sf = sfeat + half * (DIM_IN / 2);
    float acc = 0.f;
#pragma unroll 8
    for (int j = 0; j < DIM_IN / 8; ++j) {   // 256 float4 per lane
        float4 wv = w4[j];
        acc += wv.x * sf[4*j] + wv.y * sf[4*j+1] + wv.z * sf[4*j+2] + wv.w * sf[4*j+3];
    }
    part[half][d] = acc;
    __syncthreads();

    if (t < 128) {
        float pre = part[0][t] + part[1][t] + bias[t];
        part[0][t] = pre;
        float sq = pre * pre;
#pragma unroll
        for (int o = 32; o > 0; o >>= 1) sq += __shfl_xor(sq, o, 64);
        if ((t & 63) == 0) wsum[t >> 6] = sq;   // one per wave (t=0, t=64)
    }
    __syncthreads();
    if (t < 128) {
        float inv_norm = 1.0f / sqrtf(wsum[0] + wsum[1]);
        v_out[(size_t)blk * FEAT + t] = part[0][t] * inv_norm;
    }
}

// ---------------------------------------------------------------------------
// Kernel 2: for each sampled row, ex = exp(dot(mem[row], v[b]) / T).
// Store ex (needed again in loss pass) and accumulate Z = sum(ex) per side.
// Block = (side*64+b)*NCHUNK + chunk; v[b] broadcast from LDS; one sample
// per lane per iteration; 32 float4 loads per sample in 4 chunks of 8 to
// bound VGPRs (~8 outstanding loads/wave) while preventing LDS-hoist of v.
// ---------------------------------------------------------------------------
__global__ void __launch_bounds__(256) nce_kernel(
    const int* __restrict__ sample_idx,
    const float* __restrict__ mem_v1, const float* __restrict__ mem_v2,
    const float* __restrict__ v_in,
    float* __restrict__ ex_out, float* __restrict__ z_out)
{
    const int blk   = blockIdx.x;
    const int chunk = blk & (NCHUNK - 1);
    const int sb    = blk / NCHUNK;        // side*64 + b
    const int side  = sb >> 6;
    const int b     = sb & 63;
    // side 0: student anchor vs teacher memory (mem_v2); side 1: vice versa
    const float* bank = (side == 0 ? mem_v2 : mem_v1);

    __shared__ float vlds[FEAT];
    const int t = threadIdx.x;
    if (t < FEAT) vlds[t] = v_in[(size_t)sb * FEAT + t];
    __syncthreads();
    const float4* v4 = (const float4*)vlds;

    float zpart = 0.f;
    for (int k = chunk * 256 + t; k < KP1; k += NCHUNK * 256) {
        const int idx = sample_idx[(size_t)b * KP1 + k];
        const float4* row = (const float4*)(bank + (size_t)idx * FEAT);
        float acc = 0.f;
#pragma unroll 1
        for (int c = 0; c < 4; ++c) {        // 4 chunks of 8 float4
            float4 r[8];
#pragma unroll
            for (int j = 0; j < 8; ++j) r[j] = row[c * 8 + j];
#pragma unroll
            for (int j = 0; j < 8; ++j) {
                float4 vv = v4[c * 8 + j];   // LDS broadcast (same addr all lanes)
                acc += r[j].x * vv.x + r[j].y * vv.y + r[j].z * vv.z + r[j].w * vv.w;
            }
        }
        float ex = __expf(acc * NCE_T_INV);
        ex_out[(size_t)sb * KP1 + k] = ex;
        zpart += ex;
    }

    // block reduce zpart -> one atomic per block
#pragma unroll
    for (int o = 32; o > 0; o >>= 1) zpart += __shfl_xor(zpart, o, 64);
    __shared__ float zw[4];
    if ((t & 63) == 0) zw[t >> 6] = zpart;
    __syncthreads();
    if (t == 0) atomicAdd(&z_out[side], zw[0] + zw[1] + zw[2] + zw[3]);
}

// ---------------------------------------------------------------------------
// Kernel 3: loss. One block per (side,b) row of ex. x = ex / Z;
// k==0: log(x/(x+m+eps)); k>0: log(m/(x+m+eps)). Sum, negate, /BATCH.
// ---------------------------------------------------------------------------
__global__ void __launch_bounds__(256) loss_kernel(
    const float* __restrict__ ex_in, const float* __restrict__ z_in,
    float* __restrict__ out)
{
    const int sb   = blockIdx.x;        // side*64 + b
    const int side = sb >> 6;
    // z = mean(ex over 64*16385) * NDATA
    const float z  = z_in[side] * ((float)NDATA / (64.0f * (float)KP1));
    const float rz = 1.0f / z;
    const float* ex = ex_in + (size_t)sb * KP1;

    float part = 0.f;
    for (int k = threadIdx.x; k < KP1; k += 256) {
        const float x = ex[k] * rz;
        if (k == 0) part += __logf(x / (x + M_CONST + EPS_C));
        else        part += __logf(M_CONST / (x + M_CONST + EPS_C));
    }
#pragma unroll
    for (int o = 32; o > 0; o >>= 1) part += __shfl_xor(part, o, 64);
    __shared__ float pw[4];
    if ((threadIdx.x & 63) == 0) pw[threadIdx.x >> 6] = part;
    __syncthreads();
    if (threadIdx.x == 0)
        atomicAdd(out, -(pw[0] + pw[1] + pw[2] + pw[3]) * (1.0f / 64.0f));
}

// ---------------------------------------------------------------------------
extern "C" void kernel_launch(void* const* d_in, const int* in_sizes, int n_in,
                              void* d_out, int out_size, void* d_ws, size_t ws_size,
                              hipStream_t stream)
{
    const float* feat_s     = (const float*)d_in[0];
    const float* feat_t     = (const float*)d_in[1];
    /* d_in[2] = idx, unused: sample_idx[:,0] already holds it */
    const int*   sample_idx = (const int*)  d_in[3];
    const float* w_s        = (const float*)d_in[4];
    const float* b_s        = (const float*)d_in[5];
    const float* w_t        = (const float*)d_in[6];
    const float* b_t        = (const float*)d_in[7];
    const float* mem_v1     = (const float*)d_in[8];
    const float* mem_v2     = (const float*)d_in[9];
    float* out = (float*)d_out;

    // Workspace layout: [z: 2 floats][pad to 256][v: 2*64*128 f32][ex: 2*64*16385 f32]
    char*  ws   = (char*)d_ws;
    float* ws_z = (float*)ws;
    float* ws_v = (float*)(ws + 256);
    float* ws_ex = (float*)(ws + 256 + 2 * BATCH * FEAT * sizeof(float));

    hipMemsetAsync(ws_z, 0, 2 * sizeof(float), stream);
    hipMemsetAsync(out, 0, sizeof(float), stream);

    embed_kernel<<<2 * BATCH, 256, 0, stream>>>(feat_s, feat_t, w_s, b_s, w_t, b_t, ws_v);
    nce_kernel<<<2 * BATCH * NCHUNK, 256, 0, stream>>>(sample_idx, mem_v1, mem_v2,
                                                       ws_v, ws_ex, ws_z);
    loss_kernel<<<2 * BATCH, 256, 0, stream>>>(ws_ex, ws_z, out);
}

// Round 2
// 296.503 us; speedup vs baseline: 1.0868x; 1.0868x over previous
//
#include <hip/hip_runtime.h>

// Problem constants (from reference)
#define DIM_IN   2048
#define FEAT     128
#define KP1      16385      // NCE_N + 1
#define NDATA    100000
#define BATCH    64
#define RT       64         // rows per block tile in dense gemm
#define NTILES   ((NDATA + RT - 1) / RT)   // 1563
#define AS       132        // LDS row stride for A (keeps b128 16B-aligned, +4 pad)
#define BS       68         // LDS row stride for B^T
#define GCH      8          // k-chunks per (side,b) in gather kernel

constexpr float NCE_T_INV = 1.0f / 0.07f;
constexpr float M_CONST   = 16384.0f / 100000.0f;   // NCE_N / N_DATA
constexpr float EPS_C     = 1e-7f;

// ---------------------------------------------------------------------------
// Kernel 1: h = l2norm(feat @ w.T + b) for both sides. (unchanged from R1)
// ---------------------------------------------------------------------------
__global__ void __launch_bounds__(256) embed_kernel(
    const float* __restrict__ feat_s, const float* __restrict__ feat_t,
    const float* __restrict__ w_s, const float* __restrict__ b_s,
    const float* __restrict__ w_t, const float* __restrict__ b_t,
    float* __restrict__ v_out)
{
    const int blk  = blockIdx.x;      // side*64 + b
    const int side = blk >> 6;
    const int b    = blk & 63;
    const float* feat = (side == 0 ? feat_s : feat_t) + (size_t)b * DIM_IN;
    const float* w    = (side == 0 ? w_s : w_t);
    const float* bias = (side == 0 ? b_s : b_t);

    __shared__ float sfeat[DIM_IN];
    __shared__ float part[2][FEAT];
    __shared__ float wsum[2];

    const int t = threadIdx.x;
    {
        const float4* f4 = (const float4*)feat;
        float4* s4 = (float4*)sfeat;
        for (int j = t; j < DIM_IN / 4; j += 256) s4[j] = f4[j];
    }
    __syncthreads();

    const int d = t & 127, half = t >> 7;
    const float4* w4 = (const float4*)(w + (size_t)d * DIM_IN + half * (DIM_IN / 2));
    const float*  sf = sfeat + half * (DIM_IN / 2);
    float acc = 0.f;
#pragma unroll 8
    for (int j = 0; j < DIM_IN / 8; ++j) {
        float4 wv = w4[j];
        acc += wv.x * sf[4*j] + wv.y * sf[4*j+1] + wv.z * sf[4*j+2] + wv.w * sf[4*j+3];
    }
    part[half][d] = acc;
    __syncthreads();

    if (t < 128) {
        float pre = part[0][t] + part[1][t] + bias[t];
        part[0][t] = pre;
        float sq = pre * pre;
#pragma unroll
        for (int o = 32; o > 0; o >>= 1) sq += __shfl_xor(sq, o, 64);
        if ((t & 63) == 0) wsum[t >> 6] = sq;
    }
    __syncthreads();
    if (t < 128) {
        float inv_norm = 1.0f / sqrtf(wsum[0] + wsum[1]);
        v_out[(size_t)blk * FEAT + t] = part[0][t] * inv_norm;
    }
}

// ---------------------------------------------------------------------------
// Kernel 2: dense skinny GEMM + exp.
// E[side][n][b] = exp( dot(bank_side[n], v[side][b]) / T ) for ALL n, b.
// bank_0 = mem_v2 (student anchors), bank_1 = mem_v1 (teacher anchors).
// Block: one side, 64-row tile, all 64 anchors; 256 thr, 4x4 accs each.
// A staged row-major (stride 132), B staged transposed [k][b] (stride 68);
// inner loop: 8x ds_read_b128 per 64 v_fma -> VALU-bound. 67 KB LDS.
// ---------------------------------------------------------------------------
__global__ void __launch_bounds__(256) gemm_exp_kernel(
    const float* __restrict__ mem_v1, const float* __restrict__ mem_v2,
    const float* __restrict__ v_in, float* __restrict__ E)
{
    __shared__ __align__(16) float sA[RT * AS];     // sA[r*AS + k]
    __shared__ __align__(16) float sB[FEAT * BS];   // sB[k*BS + b]

    const int bx   = blockIdx.x;
    const int side = bx & 1;
    const int tile = bx >> 1;
    const int row0 = tile * RT;
    const float* bank = (side == 0 ? mem_v2 : mem_v1);
    const float* vb   = v_in + (size_t)side * 64 * FEAT;
    const int t = threadIdx.x;

    // stage A: coalesced float4 global reads, b128 LDS writes
    for (int i = t; i < RT * (FEAT / 4); i += 256) {   // 2048 float4
        const int r = i >> 5;          // 0..63
        const int f = i & 31;          // float4 index within row
        int row = row0 + r; if (row >= NDATA) row = NDATA - 1;  // clamp (stores guarded)
        float4 a = ((const float4*)(bank + (size_t)row * FEAT))[f];
        *(float4*)&sA[r * AS + f * 4] = a;
    }
    // stage B transposed: sB[k][b] = v[b][k]
    for (int i = t; i < 64 * (FEAT / 4); i += 256) {
        const int b2 = i >> 5;
        const int f  = i & 31;
        float4 v4 = ((const float4*)(vb + (size_t)b2 * FEAT))[f];
        sB[(f * 4 + 0) * BS + b2] = v4.x;
        sB[(f * 4 + 1) * BS + b2] = v4.y;
        sB[(f * 4 + 2) * BS + b2] = v4.z;
        sB[(f * 4 + 3) * BS + b2] = v4.w;
    }
    __syncthreads();

    const int rg = t >> 4;    // row group: rows rg*4 .. rg*4+3
    const int ag = t & 15;    // anchor group: anchors ag*4 .. ag*4+3
    float acc[4][4] = {{0.f}};

#pragma unroll 4
    for (int k = 0; k < FEAT; k += 4) {
        float a[4][4];   // a[i][c] = A[rg*4+i][k+c]
        float bb[4][4];  // bb[c][j] = B^T[k+c][ag*4+j]
#pragma unroll
        for (int i = 0; i < 4; ++i)
            *(float4*)&a[i][0] = *(const float4*)&sA[(rg * 4 + i) * AS + k];
#pragma unroll
        for (int c = 0; c < 4; ++c)
            *(float4*)&bb[c][0] = *(const float4*)&sB[(k + c) * BS + ag * 4];
#pragma unroll
        for (int c = 0; c < 4; ++c)
#pragma unroll
            for (int i = 0; i < 4; ++i)
#pragma unroll
                for (int j = 0; j < 4; ++j)
                    acc[i][j] += a[i][c] * bb[c][j];
    }

    // epilogue: exp + coalesced float4 store
#pragma unroll
    for (int i = 0; i < 4; ++i) {
        const int row = row0 + rg * 4 + i;
        if (row < NDATA) {
            float4 o;
            o.x = __expf(acc[i][0] * NCE_T_INV);
            o.y = __expf(acc[i][1] * NCE_T_INV);
            o.z = __expf(acc[i][2] * NCE_T_INV);
            o.w = __expf(acc[i][3] * NCE_T_INV);
            *(float4*)&E[((size_t)side * NDATA + row) * 64 + ag * 4] = o;
        }
    }
}

// ---------------------------------------------------------------------------
// Kernel 3: gather ex = E[side][idx[b,k]][b], store compact, accumulate Z.
// ---------------------------------------------------------------------------
__global__ void __launch_bounds__(256) gather_z_kernel(
    const int* __restrict__ sample_idx, const float* __restrict__ E,
    float* __restrict__ ex_out, float* __restrict__ z_out)
{
    const int blk   = blockIdx.x;
    const int chunk = blk & (GCH - 1);
    const int sb    = blk / GCH;         // side*64 + b
    const int side  = sb >> 6;
    const int b     = sb & 63;
    const float* Eb = E + (size_t)side * NDATA * 64 + b;

    float zp = 0.f;
    for (int k = chunk * 256 + threadIdx.x; k < KP1; k += GCH * 256) {
        const int idx = sample_idx[(size_t)b * KP1 + k];
        const float e = Eb[(size_t)idx * 64];
        ex_out[(size_t)sb * KP1 + k] = e;
        zp += e;
    }
#pragma unroll
    for (int o = 32; o > 0; o >>= 1) zp += __shfl_xor(zp, o, 64);
    __shared__ float zw[4];
    if ((threadIdx.x & 63) == 0) zw[threadIdx.x >> 6] = zp;
    __syncthreads();
    if (threadIdx.x == 0) atomicAdd(&z_out[side], zw[0] + zw[1] + zw[2] + zw[3]);
}

// ---------------------------------------------------------------------------
// Kernel 4: loss from compact ex + Z. (unchanged from R1)
// ---------------------------------------------------------------------------
__global__ void __launch_bounds__(256) loss_kernel(
    const float* __restrict__ ex_in, const float* __restrict__ z_in,
    float* __restrict__ out)
{
    const int sb   = blockIdx.x;        // side*64 + b
    const int side = sb >> 6;
    const float z  = z_in[side] * ((float)NDATA / (64.0f * (float)KP1));
    const float rz = 1.0f / z;
    const float* ex = ex_in + (size_t)sb * KP1;

    float part = 0.f;
    for (int k = threadIdx.x; k < KP1; k += 256) {
        const float x = ex[k] * rz;
        if (k == 0) part += __logf(x / (x + M_CONST + EPS_C));
        else        part += __logf(M_CONST / (x + M_CONST + EPS_C));
    }
#pragma unroll
    for (int o = 32; o > 0; o >>= 1) part += __shfl_xor(part, o, 64);
    __shared__ float pw[4];
    if ((threadIdx.x & 63) == 0) pw[threadIdx.x >> 6] = part;
    __syncthreads();
    if (threadIdx.x == 0)
        atomicAdd(out, -(pw[0] + pw[1] + pw[2] + pw[3]) * (1.0f / 64.0f));
}

// ---------------------------------------------------------------------------
extern "C" void kernel_launch(void* const* d_in, const int* in_sizes, int n_in,
                              void* d_out, int out_size, void* d_ws, size_t ws_size,
                              hipStream_t stream)
{
    const float* feat_s     = (const float*)d_in[0];
    const float* feat_t     = (const float*)d_in[1];
    /* d_in[2] = idx, unused: sample_idx[:,0] already holds it */
    const int*   sample_idx = (const int*)  d_in[3];
    const float* w_s        = (const float*)d_in[4];
    const float* b_s        = (const float*)d_in[5];
    const float* w_t        = (const float*)d_in[6];
    const float* b_t        = (const float*)d_in[7];
    const float* mem_v1     = (const float*)d_in[8];
    const float* mem_v2     = (const float*)d_in[9];
    float* out = (float*)d_out;

    // Workspace layout:
    //   [z: 2 f32][pad to 256]
    //   [v: 2*64*128 f32 = 64 KB]
    //   [ex: 2*64*16385 f32 = 8.39 MB]
    //   [E: 2*100000*64 f32 = 51.2 MB]
    char*  ws    = (char*)d_ws;
    float* ws_z  = (float*)ws;
    float* ws_v  = (float*)(ws + 256);
    float* ws_ex = (float*)(ws + 256 + 2 * BATCH * FEAT * sizeof(float));
    float* ws_E  = (float*)(ws + 256 + 2 * BATCH * FEAT * sizeof(float)
                               + (size_t)2 * BATCH * KP1 * sizeof(float));

    hipMemsetAsync(ws_z, 0, 2 * sizeof(float), stream);
    hipMemsetAsync(out, 0, sizeof(float), stream);

    embed_kernel<<<2 * BATCH, 256, 0, stream>>>(feat_s, feat_t, w_s, b_s, w_t, b_t, ws_v);
    gemm_exp_kernel<<<2 * NTILES, 256, 0, stream>>>(mem_v1, mem_v2, ws_v, ws_E);
    gather_z_kernel<<<2 * BATCH * GCH, 256, 0, stream>>>(sample_idx, ws_E, ws_ex, ws_z);
    loss_kernel<<<2 * BATCH, 256, 0, stream>>>(ws_ex, ws_z, out);
}